// Round 6
// baseline (736.329 us; speedup 1.0000x reference)
//
#include <hip/hip_runtime.h>
#include <hip/hip_fp16.h>
#include <math.h>

#define N_TOK 8192
#define D_DIM 1024
#define H_DIM 2048
#define N_EXP 8
#define CAPL  8192
#define MT1   18      // m-tiles per expert (capacity 2304 rows; cnt ~ 2048 +- 39)

typedef _Float16 f16x8 __attribute__((ext_vector_type(8)));
typedef float    f32x4 __attribute__((ext_vector_type(4)));

__device__ __forceinline__ void gload16(const void* g, void* l) {
  __builtin_amdgcn_global_load_lds(
      (const __attribute__((address_space(1))) void*)g,
      (__attribute__((address_space(3))) void*)l, 16, 0, 0);
}

// ---------------- x: fp32 -> fp16, linear ----------------
__global__ __launch_bounds__(256) void cvt_f32_f16(const float* __restrict__ s,
                                                   _Float16* __restrict__ d, int n4) {
  int i = blockIdx.x * 256 + threadIdx.x;
  if (i >= n4) return;
  float4 v = ((const float4*)s)[i];
  _Float16 o0 = (_Float16)v.x, o1 = (_Float16)v.y, o2 = (_Float16)v.z, o3 = (_Float16)v.w;
  __attribute__((ext_vector_type(4))) _Float16 o = {o0, o1, o2, o3};
  ((__attribute__((ext_vector_type(4))) _Float16*)d)[i] = o;
}

// ---- weights: [E][R][K] fp32 -> tile-packed [E][R/128][K/32][128*32] fp16 ----
__global__ __launch_bounds__(256) void pack_w(const float* __restrict__ src,
                                              _Float16* __restrict__ dst,
                                              int R, int K) {
  const int e = blockIdx.z, rt = blockIdx.y, kc = blockIdx.x;
  const int t = threadIdx.x;
  const int r = t >> 1, c = (t & 1) * 16;
  const float* s = src + ((long)e * R + (long)rt * 128 + r) * K + kc * 32 + c;
  const float4 v0 = ((const float4*)s)[0];
  const float4 v1 = ((const float4*)s)[1];
  const float4 v2 = ((const float4*)s)[2];
  const float4 v3 = ((const float4*)s)[3];
  f16x8 o0, o1;
  o0[0]=(_Float16)v0.x; o0[1]=(_Float16)v0.y; o0[2]=(_Float16)v0.z; o0[3]=(_Float16)v0.w;
  o0[4]=(_Float16)v1.x; o0[5]=(_Float16)v1.y; o0[6]=(_Float16)v1.z; o0[7]=(_Float16)v1.w;
  o1[0]=(_Float16)v2.x; o1[1]=(_Float16)v2.y; o1[2]=(_Float16)v2.z; o1[3]=(_Float16)v2.w;
  o1[4]=(_Float16)v3.x; o1[5]=(_Float16)v3.y; o1[6]=(_Float16)v3.z; o1[7]=(_Float16)v3.w;
  _Float16* d = dst + (((long)e * (R >> 7) + rt) * (K >> 5) + kc) * 4096 + t * 16;
  ((f16x8*)d)[0] = o0;
  ((f16x8*)d)[1] = o1;
}

// ---------------- gating: fp64 acc -> exact top-2, NO atomics ----------------
__global__ __launch_bounds__(256) void gate_compute(
    const float* __restrict__ x, const float* __restrict__ gw,
    const float* __restrict__ gb, int* __restrict__ e12,
    float2* __restrict__ pp) {
  __shared__ float sgw[N_EXP * D_DIM];
  for (int i = threadIdx.x; i < N_EXP * D_DIM; i += 256) sgw[i] = gw[i];
  __syncthreads();
  const int w = threadIdx.x >> 6, lane = threadIdx.x & 63;
  const int n = blockIdx.x * 4 + w;
  const float* xp = x + (long)n * D_DIM;
  double acc[N_EXP];
  #pragma unroll
  for (int e = 0; e < N_EXP; e++) acc[e] = 0.0;
  for (int i = 0; i < D_DIM / 64; i++) {
    int d = lane + i * 64;
    double xv = (double)xp[d];
    #pragma unroll
    for (int e = 0; e < N_EXP; e++) acc[e] += xv * (double)sgw[e * D_DIM + d];
  }
  #pragma unroll
  for (int e = 0; e < N_EXP; e++)
    for (int off = 32; off >= 1; off >>= 1)
      acc[e] += __shfl_down(acc[e], off);
  if (lane == 0) {
    double lg[N_EXP];
    #pragma unroll
    for (int e = 0; e < N_EXP; e++) lg[e] = acc[e] + (double)gb[e];
    int i1 = 0;
    for (int e = 1; e < N_EXP; e++) if (lg[e] > lg[i1]) i1 = e;
    int i2 = (i1 == 0) ? 1 : 0;
    for (int e = 0; e < N_EXP; e++) { if (e == i1) continue; if (lg[e] > lg[i2]) i2 = e; }
    double p1 = 1.0 / (1.0 + exp(lg[i2] - lg[i1]));
    double p2 = 1.0 - p1;
    e12[n] = i1 | (i2 << 8);
    pp[n] = make_float2((float)p1, (float)p2);
  }
}

// ---------------- list compaction: 1 block per expert, ballot prefix-sum ----
__global__ __launch_bounds__(256) void build_lists(
    const int* __restrict__ e12, const float2* __restrict__ pp,
    int* __restrict__ cnt, int* __restrict__ tokL, float* __restrict__ coefL) {
  const int e = blockIdx.x;
  __shared__ int sbase;
  __shared__ int wsum[4];
  const int w = threadIdx.x >> 6, lane = threadIdx.x & 63;
  if (threadIdx.x == 0) sbase = 0;
  __syncthreads();
  for (int c0 = 0; c0 < N_TOK; c0 += 256) {
    const int n = c0 + threadIdx.x;
    const int v = e12[n];
    const float2 pv = pp[n];
    int slot = -1;
    float p = 0.f;
    if ((v & 255) == e)      { slot = 0; p = pv.x; }
    else if ((v >> 8) == e)  { slot = 1; p = pv.y; }
    const unsigned long long m = __ballot(slot >= 0);
    if (lane == 0) wsum[w] = __popcll(m);
    __syncthreads();
    int wbase = sbase;
    #pragma unroll
    for (int i = 0; i < 4; i++) if (i < w) wbase += wsum[i];
    const int total = wsum[0] + wsum[1] + wsum[2] + wsum[3];
    if (slot >= 0) {
      const int pos = wbase + __popcll(m & ((1ull << lane) - 1ull));
      tokL[e * CAPL + pos] = n * 2 + slot;
      coefL[e * CAPL + pos] = p;
    }
    __syncthreads();
    if (threadIdx.x == 0) sbase += total;  // total read before this barrier pair reopens
  }
  __syncthreads();
  if (threadIdx.x == 0) cnt[e] = sbase;
}

// ---------------- stage 1: h = relu(x@W1^T)^2 * (x@W3^T) ----------------
// Single-role T3 2-phase: 256 threads, ALL waves stage (6 x 16B gload_lds)
// AND compute. Per iter: issue STAGE(buf^1) -> ds_read buf -> 32 MFMA ->
// __syncthreads (vmcnt drain lands ~450cy after issue, covered by MFMA).
// Round-5 lesson: residency is AGPR-bound (not LDS), and exposed load
// latency costs ~60us -> overlap staging in-wave instead of via dedicated
// producer waves (which serialized vmcnt stall + 6-wave rendezvous).
// Double-buffered LDS 48.5KB; XCD-aware block remap; XOR bank swizzle.
__global__ __launch_bounds__(256, 2) void ffn_stage1(
    const _Float16* __restrict__ xh, const _Float16* __restrict__ w1p,
    const _Float16* __restrict__ w3p, const int* __restrict__ cnt,
    const int* __restrict__ tokL, _Float16* __restrict__ hbuf) {
  const int lin = blockIdx.x;
  const int xcd = lin & 7;
  const int j   = lin >> 3;        // 0..287
  const int mt  = j % MT1;
  const int gi  = j / MT1;         // 0..15
  const int g   = gi * 8 + xcd;    // 0..127 weight-tile group
  const int nt  = g & 15;
  const int e   = g >> 4;
  const int m0 = mt * 128;
  const int c = cnt[e];
  if (m0 >= c) return;

  __shared__ _Float16 Xs[2][4096];
  __shared__ _Float16 W1s[2][4096];
  __shared__ _Float16 W3s[2][4096];
  __shared__ int sEnt[128];

  const int t = threadIdx.x;
  if (t < 128) {
    int idx = m0 + t; if (idx >= c) idx = c - 1;   // clamp; stores guarded later
    sEnt[t] = tokL[e * CAPL + idx];
  }
  __syncthreads();

  // -------- staging setup (all 256 threads, 6 x 16B per K-iter) --------
  // LDS chunk at f16-offset t*8 + j2*2048 covers rows r = (t>>2) + 64*j2.
  // Source XOR swizzle term ((r>>1)&3) == ((t>>3)&3), j2-invariant.
  const int swz = ((t & 3) ^ ((t >> 3) & 3)) * 8;
  const _Float16* xsrcA = xh + (long)(sEnt[t >> 2] >> 1) * D_DIM + swz;
  const _Float16* xsrcB = xh + (long)(sEnt[(t >> 2) + 64] >> 1) * D_DIM + swz;
  const int po = (t >> 2) * 32 + swz;
  const _Float16* w1t = w1p + (long)(e * 16 + nt) * 32 * 4096 + po;
  const _Float16* w3t = w3p + (long)(e * 16 + nt) * 32 * 4096 + po;
  const int l0 = t * 8;                              // 16B per thread, linear

  auto stage = [&](int b, int kc) {
    gload16(xsrcA + kc * 32, &Xs[b][l0]);
    gload16(xsrcB + kc * 32, &Xs[b][l0 + 2048]);
    gload16(w1t + (long)kc * 4096, &W1s[b][l0]);
    gload16(w1t + (long)kc * 4096 + 2048, &W1s[b][l0 + 2048]);
    gload16(w3t + (long)kc * 4096, &W3s[b][l0]);
    gload16(w3t + (long)kc * 4096 + 2048, &W3s[b][l0 + 2048]);
  };

  // -------- consumers: 4 waves, 128x128 tile, dual GEMM --------
  const int w = t >> 6, lane = t & 63;
  const int wm = (w & 1) * 64, wn = (w >> 1) * 64;
  const int q = lane >> 4, lr = lane & 15;
  const int qs = (q ^ ((lr >> 1) & 3)) * 8;             // read-side XOR swizzle

  f32x4 au[4][4], av[4][4];
  const f32x4 zz = {0.f, 0.f, 0.f, 0.f};
  #pragma unroll
  for (int i = 0; i < 4; i++)
    #pragma unroll
    for (int j2 = 0; j2 < 4; j2++) { au[i][j2] = zz; av[i][j2] = zz; }

  stage(0, 0);
  __syncthreads();                     // buf0 ready (vmcnt drained)
  for (int kc = 0; kc < 32; ++kc) {
    if (kc + 1 < 32) stage((kc + 1) & 1, kc + 1);
    const int p = kc & 1;
    f16x8 a[4], b1[4], b3[4];
    #pragma unroll
    for (int i = 0; i < 4; i++) {
      a[i]  = *(const f16x8*)(&Xs[p][(wm + i * 16 + lr) * 32 + qs]);
      b1[i] = *(const f16x8*)(&W1s[p][(wn + i * 16 + lr) * 32 + qs]);
      b3[i] = *(const f16x8*)(&W3s[p][(wn + i * 16 + lr) * 32 + qs]);
    }
    #pragma unroll
    for (int mi = 0; mi < 4; mi++)
      #pragma unroll
      for (int ni = 0; ni < 4; ni++) {
        au[mi][ni] = __builtin_amdgcn_mfma_f32_16x16x32_f16(a[mi], b1[ni], au[mi][ni], 0, 0, 0);
        av[mi][ni] = __builtin_amdgcn_mfma_f32_16x16x32_f16(a[mi], b3[ni], av[mi][ni], 0, 0, 0);
      }
    __syncthreads();                   // buf kc+1 ready; buf kc free
  }

  // epilogue: packed h tile (e, mt), kchunks nt*4 .. nt*4+3, row = list position
  const long tb = ((long)(e * MT1 + mt) * 64 + nt * 4) * 4096;
  #pragma unroll
  for (int mi = 0; mi < 4; mi++) {
    #pragma unroll
    for (int r = 0; r < 4; r++) {
      int ml = wm + mi * 16 + q * 4 + r;
      if (m0 + ml < c) {
        #pragma unroll
        for (int ni = 0; ni < 4; ni++) {
          int colb = wn + ni * 16;
          float u = au[mi][ni][r];
          float rl = u > 0.f ? u : 0.f;
          float hv = rl * rl * av[mi][ni][r];
          hbuf[tb + (long)(colb >> 5) * 4096 + ml * 32 + (colb & 31) + lr] = (_Float16)hv;
        }
      }
    }
  }
}

// ---------------- stage 2: out += coef * (h @ W2^T), split-K x2 ----------------
// Same single-role 2-phase structure: 256 threads, 4 x 16B gload_lds per iter.
__global__ __launch_bounds__(256, 3) void ffn_stage2(
    const _Float16* __restrict__ hbuf, const _Float16* __restrict__ w2p,
    const int* __restrict__ cnt, const int* __restrict__ tokL,
    const float* __restrict__ coefL, float* __restrict__ out) {
  const int lin = blockIdx.x;
  const int xcd = lin & 7;
  const int j   = lin >> 3;        // 0..287
  const int mt  = j % MT1;
  const int gi  = j / MT1;         // 0..15
  const int g   = gi * 8 + xcd;    // 0..127 -> (dt, e, ks)
  const int dt  = g & 7;
  const int ezk = g >> 3;          // 0..15
  const int e   = ezk >> 1, ks = ezk & 1;
  const int m0 = mt * 128;
  const int c = cnt[e];
  if (m0 >= c) return;

  __shared__ _Float16 Hs[2][4096];
  __shared__ _Float16 W2s[2][4096];
  __shared__ int sEnt[128];
  __shared__ float sCoef[128];

  const int t = threadIdx.x;
  if (t < 128) {
    int idx = m0 + t; if (idx >= c) idx = c - 1;
    sEnt[t]  = tokL[e * CAPL + idx];
    sCoef[t] = coefL[e * CAPL + idx];
  }
  __syncthreads();

  const int swz = ((t & 3) ^ ((t >> 3) & 3)) * 8;   // source-side XOR swizzle
  const int po = (t >> 2) * 32 + swz;
  const _Float16* hA  = hbuf + ((long)(e * MT1 + mt) * 64 + ks * 32) * 4096 + po;
  const _Float16* w2t = w2p  + ((long)(e * 8 + dt) * 64 + ks * 32) * 4096 + po;
  const int l0 = t * 8;

  auto stage = [&](int b, int kc) {
    gload16(hA + (long)kc * 4096, &Hs[b][l0]);
    gload16(hA + (long)kc * 4096 + 2048, &Hs[b][l0 + 2048]);
    gload16(w2t + (long)kc * 4096, &W2s[b][l0]);
    gload16(w2t + (long)kc * 4096 + 2048, &W2s[b][l0 + 2048]);
  };

  const int w = t >> 6, lane = t & 63;
  const int wm = (w & 1) * 64, wn = (w >> 1) * 64;
  const int q = lane >> 4, lr = lane & 15;
  const int qs = (q ^ ((lr >> 1) & 3)) * 8;             // read-side XOR swizzle

  f32x4 ac[4][4];
  const f32x4 zz = {0.f, 0.f, 0.f, 0.f};
  #pragma unroll
  for (int i = 0; i < 4; i++)
    #pragma unroll
    for (int j2 = 0; j2 < 4; j2++) ac[i][j2] = zz;

  stage(0, 0);
  __syncthreads();
  for (int kc = 0; kc < 32; ++kc) {
    if (kc + 1 < 32) stage((kc + 1) & 1, kc + 1);
    const int p = kc & 1;
    f16x8 a[4], b[4];
    #pragma unroll
    for (int i = 0; i < 4; i++) {
      a[i] = *(const f16x8*)(&Hs[p][(wm + i * 16 + lr) * 32 + qs]);
      b[i] = *(const f16x8*)(&W2s[p][(wn + i * 16 + lr) * 32 + qs]);
    }
    #pragma unroll
    for (int mi = 0; mi < 4; mi++)
      #pragma unroll
      for (int ni = 0; ni < 4; ni++)
        ac[mi][ni] = __builtin_amdgcn_mfma_f32_16x16x32_f16(a[mi], b[ni], ac[mi][ni], 0, 0, 0);
    __syncthreads();
  }

  const int n0 = dt * 128;
  #pragma unroll
  for (int mi = 0; mi < 4; mi++) {
    #pragma unroll
    for (int r = 0; r < 4; r++) {
      int ml = wm + mi * 16 + q * 4 + r;
      if (m0 + ml < c) {
        int token = sEnt[ml] >> 1;
        float cf = sCoef[ml];
        float* op = out + (long)token * D_DIM + n0 + wn + lr;
        #pragma unroll
        for (int ni = 0; ni < 4; ni++)
          atomicAdd(op + ni * 16, cf * ac[mi][ni][r]);
      }
    }
  }
}

extern "C" void kernel_launch(void* const* d_in, const int* in_sizes, int n_in,
                              void* d_out, int out_size, void* d_ws, size_t ws_size,
                              hipStream_t stream) {
  (void)in_sizes; (void)n_in; (void)out_size; (void)ws_size;
  const float* x  = (const float*)d_in[0];
  const float* W1 = (const float*)d_in[1];
  const float* W2 = (const float*)d_in[2];   // dict order: x, W1, W2, W3, gate_w, gate_b
  const float* W3 = (const float*)d_in[3];
  const float* gw = (const float*)d_in[4];
  const float* gb = (const float*)d_in[5];
  float* out = (float*)d_out;

  // workspace layout (fp16 elements), ~194 MB total
  _Float16* xh  = (_Float16*)d_ws;
  _Float16* w1p = xh  + (size_t)N_TOK * D_DIM;
  _Float16* w3p = w1p + (size_t)N_EXP * H_DIM * D_DIM;
  _Float16* w2p = w3p + (size_t)N_EXP * H_DIM * D_DIM;
  _Float16* hb  = w2p + (size_t)N_EXP * H_DIM * D_DIM;           // packed: E*MT1*64*4096
  int*   cnt   = (int*)(hb + (size_t)N_EXP * MT1 * 64 * 4096);
  int*   tokL  = cnt + 16;
  float* coefL = (float*)(tokL + N_EXP * CAPL);
  int*   e12   = (int*)(coefL + N_EXP * CAPL);                   // +32 KB
  float2* pp   = (float2*)(e12 + N_TOK);                         // +64 KB

  hipMemsetAsync(d_out, 0, (size_t)N_TOK * D_DIM * sizeof(float), stream);

  int xn4 = N_TOK * D_DIM / 4;
  cvt_f32_f16<<<(xn4 + 255) / 256, 256, 0, stream>>>(x, xh, xn4);
  pack_w<<<dim3(D_DIM / 32, H_DIM / 128, N_EXP), 256, 0, stream>>>(W1, w1p, H_DIM, D_DIM);
  pack_w<<<dim3(D_DIM / 32, H_DIM / 128, N_EXP), 256, 0, stream>>>(W3, w3p, H_DIM, D_DIM);
  pack_w<<<dim3(H_DIM / 32, D_DIM / 128, N_EXP), 256, 0, stream>>>(W2, w2p, D_DIM, H_DIM);

  gate_compute<<<N_TOK / 4, 256, 0, stream>>>(x, gw, gb, e12, pp);
  build_lists<<<N_EXP, 256, 0, stream>>>(e12, pp, cnt, tokL, coefL);

  ffn_stage1<<<MT1 * 16 * N_EXP, 256, 0, stream>>>(xh, w1p, w3p, cnt, tokL, hb);
  ffn_stage2<<<MT1 * 8 * N_EXP * 2, 256, 0, stream>>>(hb, w2p, cnt, tokL, coefL, out);
}

// Round 7
// 621.987 us; speedup vs baseline: 1.1838x; 1.1838x over previous
//
#include <hip/hip_runtime.h>
#include <hip/hip_fp16.h>
#include <math.h>

#define N_TOK 8192
#define D_DIM 1024
#define H_DIM 2048
#define N_EXP 8
#define CAPL  8192
#define MT1   18      // m-tiles per expert (capacity 2304 rows; cnt ~ 2048 +- 39)

typedef _Float16 f16x8 __attribute__((ext_vector_type(8)));
typedef float    f32x4 __attribute__((ext_vector_type(4)));

__device__ __forceinline__ void gload16(const void* g, void* l) {
  __builtin_amdgcn_global_load_lds(
      (const __attribute__((address_space(1))) void*)g,
      (__attribute__((address_space(3))) void*)l, 16, 0, 0);
}

// ---------------- x: fp32 -> fp16, linear ----------------
__global__ __launch_bounds__(256) void cvt_f32_f16(const float* __restrict__ s,
                                                   _Float16* __restrict__ d, int n4) {
  int i = blockIdx.x * 256 + threadIdx.x;
  if (i >= n4) return;
  float4 v = ((const float4*)s)[i];
  _Float16 o0 = (_Float16)v.x, o1 = (_Float16)v.y, o2 = (_Float16)v.z, o3 = (_Float16)v.w;
  __attribute__((ext_vector_type(4))) _Float16 o = {o0, o1, o2, o3};
  ((__attribute__((ext_vector_type(4))) _Float16*)d)[i] = o;
}

// ---- weights: [E][R][K] fp32 -> tile-packed [E][R/128][K/32][128*32] fp16 ----
__global__ __launch_bounds__(256) void pack_w(const float* __restrict__ src,
                                              _Float16* __restrict__ dst,
                                              int R, int K) {
  const int e = blockIdx.z, rt = blockIdx.y, kc = blockIdx.x;
  const int t = threadIdx.x;
  const int r = t >> 1, c = (t & 1) * 16;
  const float* s = src + ((long)e * R + (long)rt * 128 + r) * K + kc * 32 + c;
  const float4 v0 = ((const float4*)s)[0];
  const float4 v1 = ((const float4*)s)[1];
  const float4 v2 = ((const float4*)s)[2];
  const float4 v3 = ((const float4*)s)[3];
  f16x8 o0, o1;
  o0[0]=(_Float16)v0.x; o0[1]=(_Float16)v0.y; o0[2]=(_Float16)v0.z; o0[3]=(_Float16)v0.w;
  o0[4]=(_Float16)v1.x; o0[5]=(_Float16)v1.y; o0[6]=(_Float16)v1.z; o0[7]=(_Float16)v1.w;
  o1[0]=(_Float16)v2.x; o1[1]=(_Float16)v2.y; o1[2]=(_Float16)v2.z; o1[3]=(_Float16)v2.w;
  o1[4]=(_Float16)v3.x; o1[5]=(_Float16)v3.y; o1[6]=(_Float16)v3.z; o1[7]=(_Float16)v3.w;
  _Float16* d = dst + (((long)e * (R >> 7) + rt) * (K >> 5) + kc) * 4096 + t * 16;
  ((f16x8*)d)[0] = o0;
  ((f16x8*)d)[1] = o1;
}

// ---------------- gating: fp64 acc -> exact top-2, NO atomics ----------------
__global__ __launch_bounds__(256) void gate_compute(
    const float* __restrict__ x, const float* __restrict__ gw,
    const float* __restrict__ gb, int* __restrict__ e12,
    float2* __restrict__ pp) {
  __shared__ float sgw[N_EXP * D_DIM];
  for (int i = threadIdx.x; i < N_EXP * D_DIM; i += 256) sgw[i] = gw[i];
  __syncthreads();
  const int w = threadIdx.x >> 6, lane = threadIdx.x & 63;
  const int n = blockIdx.x * 4 + w;
  const float* xp = x + (long)n * D_DIM;
  double acc[N_EXP];
  #pragma unroll
  for (int e = 0; e < N_EXP; e++) acc[e] = 0.0;
  for (int i = 0; i < D_DIM / 64; i++) {
    int d = lane + i * 64;
    double xv = (double)xp[d];
    #pragma unroll
    for (int e = 0; e < N_EXP; e++) acc[e] += xv * (double)sgw[e * D_DIM + d];
  }
  #pragma unroll
  for (int e = 0; e < N_EXP; e++)
    for (int off = 32; off >= 1; off >>= 1)
      acc[e] += __shfl_down(acc[e], off);
  if (lane == 0) {
    double lg[N_EXP];
    #pragma unroll
    for (int e = 0; e < N_EXP; e++) lg[e] = acc[e] + (double)gb[e];
    int i1 = 0;
    for (int e = 1; e < N_EXP; e++) if (lg[e] > lg[i1]) i1 = e;
    int i2 = (i1 == 0) ? 1 : 0;
    for (int e = 0; e < N_EXP; e++) { if (e == i1) continue; if (lg[e] > lg[i2]) i2 = e; }
    double p1 = 1.0 / (1.0 + exp(lg[i2] - lg[i1]));
    double p2 = 1.0 - p1;
    e12[n] = i1 | (i2 << 8);
    pp[n] = make_float2((float)p1, (float)p2);
  }
}

// ---------------- list compaction: 1 block per expert, ballot prefix-sum ----
__global__ __launch_bounds__(256) void build_lists(
    const int* __restrict__ e12, const float2* __restrict__ pp,
    int* __restrict__ cnt, int* __restrict__ tokL, float* __restrict__ coefL) {
  const int e = blockIdx.x;
  __shared__ int sbase;
  __shared__ int wsum[4];
  const int w = threadIdx.x >> 6, lane = threadIdx.x & 63;
  if (threadIdx.x == 0) sbase = 0;
  __syncthreads();
  for (int c0 = 0; c0 < N_TOK; c0 += 256) {
    const int n = c0 + threadIdx.x;
    const int v = e12[n];
    const float2 pv = pp[n];
    int slot = -1;
    float p = 0.f;
    if ((v & 255) == e)      { slot = 0; p = pv.x; }
    else if ((v >> 8) == e)  { slot = 1; p = pv.y; }
    const unsigned long long m = __ballot(slot >= 0);
    if (lane == 0) wsum[w] = __popcll(m);
    __syncthreads();
    int wbase = sbase;
    #pragma unroll
    for (int i = 0; i < 4; i++) if (i < w) wbase += wsum[i];
    const int total = wsum[0] + wsum[1] + wsum[2] + wsum[3];
    if (slot >= 0) {
      const int pos = wbase + __popcll(m & ((1ull << lane) - 1ull));
      tokL[e * CAPL + pos] = n * 2 + slot;
      coefL[e * CAPL + pos] = p;
    }
    __syncthreads();
    if (threadIdx.x == 0) sbase += total;  // total read before this barrier pair reopens
  }
  __syncthreads();
  if (threadIdx.x == 0) cnt[e] = sbase;
}

// ---------------- stage 1: h = relu(x@W1^T)^2 * (x@W3^T) ----------------
// 640 threads: waves 0-7 = MFMA consumers (64x32 tile each -> ~96 core regs,
// half the old 220), waves 8-9 = loaders (producer, 12 x 16B/iter).
// Round-6 lesson: the 183us floor was ONE resident block/CU because the old
// 64x64 dual-GEMM consumer wave held 128 acc AGPRs + 92 VGPRs (2 waves/SIMD
// reg cap, 1 MFMA wave/SIMD -> nothing overlaps its own LDS latency).
// Halving the per-wave tile doubles MFMA waves/SIMD at constant total work
// and makes 2 blocks/CU register-feasible. Producer/consumer split with
// counted vmcnt(12) kept verbatim (rounds 5/6 proved it's the only structure
// that keeps loads in flight across barriers). Triple-buffer, XCD remap,
// XOR bank swizzle unchanged.
__global__ __launch_bounds__(640, 4) void ffn_stage1(
    const _Float16* __restrict__ xh, const _Float16* __restrict__ w1p,
    const _Float16* __restrict__ w3p, const int* __restrict__ cnt,
    const int* __restrict__ tokL, _Float16* __restrict__ hbuf) {
  const int lin = blockIdx.x;
  const int xcd = lin & 7;
  const int j   = lin >> 3;        // 0..287
  const int mt  = j % MT1;
  const int gi  = j / MT1;         // 0..15
  const int g   = gi * 8 + xcd;    // 0..127 weight-tile group
  const int nt  = g & 15;
  const int e   = g >> 4;
  const int m0 = mt * 128;
  const int c = cnt[e];
  if (m0 >= c) return;

  __shared__ _Float16 Xs[3][4096];
  __shared__ _Float16 W1s[3][4096];
  __shared__ _Float16 W3s[3][4096];
  __shared__ int sEnt[128];

  const int t = threadIdx.x;
  if (t < 128) {
    int idx = m0 + t; if (idx >= c) idx = c - 1;   // clamp; stores guarded later
    sEnt[t] = tokL[e * CAPL + idx];
  }
  __syncthreads();

  if (t >= 512) {
    // -------- producer: 128 threads, 12 x 16B loads per K-iter --------
    const int pt = t - 512;
    const int swz = ((pt & 3) ^ ((pt >> 3) & 3)) * 8;   // source-side XOR swizzle
    const _Float16* xsrc[4];
    #pragma unroll
    for (int j2 = 0; j2 < 4; j2++)
      xsrc[j2] = xh + (long)(sEnt[(pt >> 2) + 32 * j2] >> 1) * D_DIM + swz;
    const int po = (pt >> 2) * 32 + swz;                // swizzled packed offset
    const _Float16* w1t = w1p + (long)(e * 16 + nt) * 32 * 4096 + po;
    const _Float16* w3t = w3p + (long)(e * 16 + nt) * 32 * 4096 + po;
    const int l0 = pt * 8;                              // LDS dest stays linear

    auto stage = [&](int b, int kc) {
      #pragma unroll
      for (int j2 = 0; j2 < 4; j2++)
        gload16(xsrc[j2] + kc * 32, &Xs[b][l0 + j2 * 1024]);
      #pragma unroll
      for (int j2 = 0; j2 < 4; j2++)
        gload16(w1t + (long)kc * 4096 + j2 * 1024, &W1s[b][l0 + j2 * 1024]);
      #pragma unroll
      for (int j2 = 0; j2 < 4; j2++)
        gload16(w3t + (long)kc * 4096 + j2 * 1024, &W3s[b][l0 + j2 * 1024]);
    };

    stage(0, 0); stage(1, 1);
    __asm__ volatile("s_waitcnt vmcnt(12)\n\ts_barrier");   // B0: buf0 ready
    for (int kc = 0; kc < 32; ++kc) {
      if (kc + 2 < 32) {
        stage((kc + 2) % 3, kc + 2);
        __asm__ volatile("s_waitcnt vmcnt(12)\n\ts_barrier");  // buf kc+1 ready
      } else {
        __asm__ volatile("s_waitcnt vmcnt(0)\n\ts_barrier");
      }
    }
    return;
  }

  // -------- consumers: 8 waves, 128x128 tile, 64x32 per wave, dual GEMM ----
  const int w = t >> 6, lane = t & 63;
  const int wm = (w & 1) * 64, wn = (w >> 1) * 32;
  const int q = lane >> 4, lr = lane & 15;
  const int qs = (q ^ ((lr >> 1) & 3)) * 8;             // read-side XOR swizzle

  f32x4 au[4][2], av[4][2];
  const f32x4 zz = {0.f, 0.f, 0.f, 0.f};
  #pragma unroll
  for (int i = 0; i < 4; i++)
    #pragma unroll
    for (int j2 = 0; j2 < 2; j2++) { au[i][j2] = zz; av[i][j2] = zz; }

  __syncthreads();                     // B0
  for (int kc = 0; kc < 32; ++kc) {
    const int p = kc % 3;
    f16x8 a[4], b1[2], b3[2];
    #pragma unroll
    for (int i = 0; i < 4; i++)
      a[i]  = *(const f16x8*)(&Xs[p][(wm + i * 16 + lr) * 32 + qs]);
    #pragma unroll
    for (int i = 0; i < 2; i++) {
      b1[i] = *(const f16x8*)(&W1s[p][(wn + i * 16 + lr) * 32 + qs]);
      b3[i] = *(const f16x8*)(&W3s[p][(wn + i * 16 + lr) * 32 + qs]);
    }
    #pragma unroll
    for (int mi = 0; mi < 4; mi++)
      #pragma unroll
      for (int ni = 0; ni < 2; ni++) {
        au[mi][ni] = __builtin_amdgcn_mfma_f32_16x16x32_f16(a[mi], b1[ni], au[mi][ni], 0, 0, 0);
        av[mi][ni] = __builtin_amdgcn_mfma_f32_16x16x32_f16(a[mi], b3[ni], av[mi][ni], 0, 0, 0);
      }
    __syncthreads();                   // B_{kc+1}
  }

  // epilogue: packed h tile (e, mt), kchunks nt*4 .. nt*4+3, row = list position
  const long tb = ((long)(e * MT1 + mt) * 64 + nt * 4) * 4096;
  #pragma unroll
  for (int mi = 0; mi < 4; mi++) {
    #pragma unroll
    for (int r = 0; r < 4; r++) {
      int ml = wm + mi * 16 + q * 4 + r;
      if (m0 + ml < c) {
        #pragma unroll
        for (int ni = 0; ni < 2; ni++) {
          int colb = wn + ni * 16;
          float u = au[mi][ni][r];
          float rl = u > 0.f ? u : 0.f;
          float hv = rl * rl * av[mi][ni][r];
          hbuf[tb + (long)(colb >> 5) * 4096 + ml * 32 + (colb & 31) + lr] = (_Float16)hv;
        }
      }
    }
  }
}

// ---------------- stage 2: out += coef * (h @ W2^T), split-K x2 ----------------
// Round-4 version (producer/consumer, triple-buffer, vmcnt(8)) restored.
__global__ __launch_bounds__(384, 3) void ffn_stage2(
    const _Float16* __restrict__ hbuf, const _Float16* __restrict__ w2p,
    const int* __restrict__ cnt, const int* __restrict__ tokL,
    const float* __restrict__ coefL, float* __restrict__ out) {
  const int lin = blockIdx.x;
  const int xcd = lin & 7;
  const int j   = lin >> 3;        // 0..287
  const int mt  = j % MT1;
  const int gi  = j / MT1;         // 0..15
  const int g   = gi * 8 + xcd;    // 0..127 -> (dt, e, ks)
  const int dt  = g & 7;
  const int ezk = g >> 3;          // 0..15
  const int e   = ezk >> 1, ks = ezk & 1;
  const int m0 = mt * 128;
  const int c = cnt[e];
  if (m0 >= c) return;

  __shared__ _Float16 Hs[3][4096];
  __shared__ _Float16 W2s[3][4096];
  __shared__ int sEnt[128];
  __shared__ float sCoef[128];

  const int t = threadIdx.x;
  if (t < 128) {
    int idx = m0 + t; if (idx >= c) idx = c - 1;
    sEnt[t]  = tokL[e * CAPL + idx];
    sCoef[t] = coefL[e * CAPL + idx];
  }
  __syncthreads();

  if (t >= 256) {
    // -------- producer: 8 x 16B loads per K-iter, all linear --------
    const int pt = t - 256;
    const int swz = ((pt & 3) ^ ((pt >> 3) & 3)) * 8;   // source-side XOR swizzle
    const int po = (pt >> 2) * 32 + swz;
    const _Float16* hA  = hbuf + ((long)(e * MT1 + mt) * 64 + ks * 32) * 4096 + po;
    const _Float16* w2t = w2p  + ((long)(e * 8 + dt) * 64 + ks * 32) * 4096 + po;
    const int l0 = pt * 8;

    auto stage = [&](int b, int kc) {
      #pragma unroll
      for (int j2 = 0; j2 < 4; j2++)
        gload16(hA + (long)kc * 4096 + j2 * 1024, &Hs[b][l0 + j2 * 1024]);
      #pragma unroll
      for (int j2 = 0; j2 < 4; j2++)
        gload16(w2t + (long)kc * 4096 + j2 * 1024, &W2s[b][l0 + j2 * 1024]);
    };

    stage(0, 0); stage(1, 1);
    __asm__ volatile("s_waitcnt vmcnt(8)\n\ts_barrier");
    for (int kc = 0; kc < 32; ++kc) {
      if (kc + 2 < 32) {
        stage((kc + 2) % 3, kc + 2);
        __asm__ volatile("s_waitcnt vmcnt(8)\n\ts_barrier");
      } else {
        __asm__ volatile("s_waitcnt vmcnt(0)\n\ts_barrier");
      }
    }
    return;
  }

  const int w = t >> 6, lane = t & 63;
  const int wm = (w & 1) * 64, wn = (w >> 1) * 64;
  const int q = lane >> 4, lr = lane & 15;
  const int qs = (q ^ ((lr >> 1) & 3)) * 8;             // read-side XOR swizzle

  f32x4 ac[4][4];
  const f32x4 zz = {0.f, 0.f, 0.f, 0.f};
  #pragma unroll
  for (int i = 0; i < 4; i++)
    #pragma unroll
    for (int j2 = 0; j2 < 4; j2++) ac[i][j2] = zz;

  __syncthreads();
  for (int kc = 0; kc < 32; ++kc) {
    const int p = kc % 3;
    f16x8 a[4], b[4];
    #pragma unroll
    for (int i = 0; i < 4; i++) {
      a[i] = *(const f16x8*)(&Hs[p][(wm + i * 16 + lr) * 32 + qs]);
      b[i] = *(const f16x8*)(&W2s[p][(wn + i * 16 + lr) * 32 + qs]);
    }
    #pragma unroll
    for (int mi = 0; mi < 4; mi++)
      #pragma unroll
      for (int ni = 0; ni < 4; ni++)
        ac[mi][ni] = __builtin_amdgcn_mfma_f32_16x16x32_f16(a[mi], b[ni], ac[mi][ni], 0, 0, 0);
    __syncthreads();
  }

  const int n0 = dt * 128;
  #pragma unroll
  for (int mi = 0; mi < 4; mi++) {
    #pragma unroll
    for (int r = 0; r < 4; r++) {
      int ml = wm + mi * 16 + q * 4 + r;
      if (m0 + ml < c) {
        int token = sEnt[ml] >> 1;
        float cf = sCoef[ml];
        float* op = out + (long)token * D_DIM + n0 + wn + lr;
        #pragma unroll
        for (int ni = 0; ni < 4; ni++)
          atomicAdd(op + ni * 16, cf * ac[mi][ni][r]);
      }
    }
  }
}

extern "C" void kernel_launch(void* const* d_in, const int* in_sizes, int n_in,
                              void* d_out, int out_size, void* d_ws, size_t ws_size,
                              hipStream_t stream) {
  (void)in_sizes; (void)n_in; (void)out_size; (void)ws_size;
  const float* x  = (const float*)d_in[0];
  const float* W1 = (const float*)d_in[1];
  const float* W2 = (const float*)d_in[2];   // dict order: x, W1, W2, W3, gate_w, gate_b
  const float* W3 = (const float*)d_in[3];
  const float* gw = (const float*)d_in[4];
  const float* gb = (const float*)d_in[5];
  float* out = (float*)d_out;

  // workspace layout (fp16 elements), ~194 MB total
  _Float16* xh  = (_Float16*)d_ws;
  _Float16* w1p = xh  + (size_t)N_TOK * D_DIM;
  _Float16* w3p = w1p + (size_t)N_EXP * H_DIM * D_DIM;
  _Float16* w2p = w3p + (size_t)N_EXP * H_DIM * D_DIM;
  _Float16* hb  = w2p + (size_t)N_EXP * H_DIM * D_DIM;           // packed: E*MT1*64*4096
  int*   cnt   = (int*)(hb + (size_t)N_EXP * MT1 * 64 * 4096);
  int*   tokL  = cnt + 16;
  float* coefL = (float*)(tokL + N_EXP * CAPL);
  int*   e12   = (int*)(coefL + N_EXP * CAPL);                   // +32 KB
  float2* pp   = (float2*)(e12 + N_TOK);                         // +64 KB

  hipMemsetAsync(d_out, 0, (size_t)N_TOK * D_DIM * sizeof(float), stream);

  int xn4 = N_TOK * D_DIM / 4;
  cvt_f32_f16<<<(xn4 + 255) / 256, 256, 0, stream>>>(x, xh, xn4);
  pack_w<<<dim3(D_DIM / 32, H_DIM / 128, N_EXP), 256, 0, stream>>>(W1, w1p, H_DIM, D_DIM);
  pack_w<<<dim3(D_DIM / 32, H_DIM / 128, N_EXP), 256, 0, stream>>>(W3, w3p, H_DIM, D_DIM);
  pack_w<<<dim3(H_DIM / 32, D_DIM / 128, N_EXP), 256, 0, stream>>>(W2, w2p, D_DIM, H_DIM);

  gate_compute<<<N_TOK / 4, 256, 0, stream>>>(x, gw, gb, e12, pp);
  build_lists<<<N_EXP, 256, 0, stream>>>(e12, pp, cnt, tokL, coefL);

  ffn_stage1<<<MT1 * 16 * N_EXP, 640, 0, stream>>>(xh, w1p, w3p, cnt, tokL, hb);
  ffn_stage2<<<MT1 * 8 * N_EXP * 2, 384, 0, stream>>>(hb, w2p, cnt, tokL, coefL, out);
}

// Round 8
// 582.826 us; speedup vs baseline: 1.2634x; 1.0672x over previous
//
#include <hip/hip_runtime.h>
#include <hip/hip_fp16.h>
#include <math.h>

#define N_TOK 8192
#define D_DIM 1024
#define H_DIM 2048
#define N_EXP 8
#define CAPL  8192
#define MT1   18      // m-tiles per expert (capacity 2304 rows; cnt ~ 2048 +- 39)
#define CAPE  (MT1 * 128)   // 2304 rows per expert in obuf

typedef _Float16 f16x8 __attribute__((ext_vector_type(8)));
typedef float    f32x4 __attribute__((ext_vector_type(4)));

__device__ __forceinline__ void gload16(const void* g, void* l) {
  __builtin_amdgcn_global_load_lds(
      (const __attribute__((address_space(1))) void*)g,
      (__attribute__((address_space(3))) void*)l, 16, 0, 0);
}

// ---------------- x: fp32 -> fp16, linear ----------------
__global__ __launch_bounds__(256) void cvt_f32_f16(const float* __restrict__ s,
                                                   _Float16* __restrict__ d, int n4) {
  int i = blockIdx.x * 256 + threadIdx.x;
  if (i >= n4) return;
  float4 v = ((const float4*)s)[i];
  _Float16 o0 = (_Float16)v.x, o1 = (_Float16)v.y, o2 = (_Float16)v.z, o3 = (_Float16)v.w;
  __attribute__((ext_vector_type(4))) _Float16 o = {o0, o1, o2, o3};
  ((__attribute__((ext_vector_type(4))) _Float16*)d)[i] = o;
}

// ---- weights: [E][R][K] fp32 -> tile-packed [E][R/128][K/32][128*32] fp16 ----
__global__ __launch_bounds__(256) void pack_w(const float* __restrict__ src,
                                              _Float16* __restrict__ dst,
                                              int R, int K) {
  const int e = blockIdx.z, rt = blockIdx.y, kc = blockIdx.x;
  const int t = threadIdx.x;
  const int r = t >> 1, c = (t & 1) * 16;
  const float* s = src + ((long)e * R + (long)rt * 128 + r) * K + kc * 32 + c;
  const float4 v0 = ((const float4*)s)[0];
  const float4 v1 = ((const float4*)s)[1];
  const float4 v2 = ((const float4*)s)[2];
  const float4 v3 = ((const float4*)s)[3];
  f16x8 o0, o1;
  o0[0]=(_Float16)v0.x; o0[1]=(_Float16)v0.y; o0[2]=(_Float16)v0.z; o0[3]=(_Float16)v0.w;
  o0[4]=(_Float16)v1.x; o0[5]=(_Float16)v1.y; o0[6]=(_Float16)v1.z; o0[7]=(_Float16)v1.w;
  o1[0]=(_Float16)v2.x; o1[1]=(_Float16)v2.y; o1[2]=(_Float16)v2.z; o1[3]=(_Float16)v2.w;
  o1[4]=(_Float16)v3.x; o1[5]=(_Float16)v3.y; o1[6]=(_Float16)v3.z; o1[7]=(_Float16)v3.w;
  _Float16* d = dst + (((long)e * (R >> 7) + rt) * (K >> 5) + kc) * 4096 + t * 16;
  ((f16x8*)d)[0] = o0;
  ((f16x8*)d)[1] = o1;
}

// ---------------- gating: fp64 acc -> exact top-2, NO atomics ----------------
__global__ __launch_bounds__(256) void gate_compute(
    const float* __restrict__ x, const float* __restrict__ gw,
    const float* __restrict__ gb, int* __restrict__ e12,
    float2* __restrict__ pp) {
  __shared__ float sgw[N_EXP * D_DIM];
  for (int i = threadIdx.x; i < N_EXP * D_DIM; i += 256) sgw[i] = gw[i];
  __syncthreads();
  const int w = threadIdx.x >> 6, lane = threadIdx.x & 63;
  const int n = blockIdx.x * 4 + w;
  const float* xp = x + (long)n * D_DIM;
  double acc[N_EXP];
  #pragma unroll
  for (int e = 0; e < N_EXP; e++) acc[e] = 0.0;
  for (int i = 0; i < D_DIM / 64; i++) {
    int d = lane + i * 64;
    double xv = (double)xp[d];
    #pragma unroll
    for (int e = 0; e < N_EXP; e++) acc[e] += xv * (double)sgw[e * D_DIM + d];
  }
  #pragma unroll
  for (int e = 0; e < N_EXP; e++)
    for (int off = 32; off >= 1; off >>= 1)
      acc[e] += __shfl_down(acc[e], off);
  if (lane == 0) {
    double lg[N_EXP];
    #pragma unroll
    for (int e = 0; e < N_EXP; e++) lg[e] = acc[e] + (double)gb[e];
    int i1 = 0;
    for (int e = 1; e < N_EXP; e++) if (lg[e] > lg[i1]) i1 = e;
    int i2 = (i1 == 0) ? 1 : 0;
    for (int e = 0; e < N_EXP; e++) { if (e == i1) continue; if (lg[e] > lg[i2]) i2 = e; }
    double p1 = 1.0 / (1.0 + exp(lg[i2] - lg[i1]));
    double p2 = 1.0 - p1;
    e12[n] = i1 | (i2 << 8);
    pp[n] = make_float2((float)p1, (float)p2);
  }
}

// ---------------- list compaction: 1 block per expert, ballot prefix-sum ----
// Also writes inv[n*2+slot] = e*CAPE + pos (token -> obuf row map for combine).
__global__ __launch_bounds__(256) void build_lists(
    const int* __restrict__ e12, const float2* __restrict__ pp,
    int* __restrict__ cnt, int* __restrict__ tokL, float* __restrict__ coefL,
    int* __restrict__ inv) {
  const int e = blockIdx.x;
  __shared__ int sbase;
  __shared__ int wsum[4];
  const int w = threadIdx.x >> 6, lane = threadIdx.x & 63;
  if (threadIdx.x == 0) sbase = 0;
  __syncthreads();
  for (int c0 = 0; c0 < N_TOK; c0 += 256) {
    const int n = c0 + threadIdx.x;
    const int v = e12[n];
    const float2 pv = pp[n];
    int slot = -1;
    float p = 0.f;
    if ((v & 255) == e)      { slot = 0; p = pv.x; }
    else if ((v >> 8) == e)  { slot = 1; p = pv.y; }
    const unsigned long long m = __ballot(slot >= 0);
    if (lane == 0) wsum[w] = __popcll(m);
    __syncthreads();
    int wbase = sbase;
    #pragma unroll
    for (int i = 0; i < 4; i++) if (i < w) wbase += wsum[i];
    const int total = wsum[0] + wsum[1] + wsum[2] + wsum[3];
    if (slot >= 0) {
      const int pos = wbase + __popcll(m & ((1ull << lane) - 1ull));
      tokL[e * CAPL + pos] = n * 2 + slot;
      coefL[e * CAPL + pos] = p;
      inv[n * 2 + slot] = e * CAPE + pos;
    }
    __syncthreads();
    if (threadIdx.x == 0) sbase += total;  // total read before this barrier pair reopens
  }
  __syncthreads();
  if (threadIdx.x == 0) cnt[e] = sbase;
}

// ---------------- stage 1: h = relu(x@W1^T)^2 * (x@W3^T) ----------------
// (round-7 version, unchanged: 640 threads, 8 consumer waves 64x32,
//  2 producer waves vmcnt(12), triple-buffer, XCD remap, XOR swizzle)
__global__ __launch_bounds__(640, 4) void ffn_stage1(
    const _Float16* __restrict__ xh, const _Float16* __restrict__ w1p,
    const _Float16* __restrict__ w3p, const int* __restrict__ cnt,
    const int* __restrict__ tokL, _Float16* __restrict__ hbuf) {
  const int lin = blockIdx.x;
  const int xcd = lin & 7;
  const int j   = lin >> 3;        // 0..287
  const int mt  = j % MT1;
  const int gi  = j / MT1;         // 0..15
  const int g   = gi * 8 + xcd;    // 0..127 weight-tile group
  const int nt  = g & 15;
  const int e   = g >> 4;
  const int m0 = mt * 128;
  const int c = cnt[e];
  if (m0 >= c) return;

  __shared__ _Float16 Xs[3][4096];
  __shared__ _Float16 W1s[3][4096];
  __shared__ _Float16 W3s[3][4096];
  __shared__ int sEnt[128];

  const int t = threadIdx.x;
  if (t < 128) {
    int idx = m0 + t; if (idx >= c) idx = c - 1;   // clamp; stores guarded later
    sEnt[t] = tokL[e * CAPL + idx];
  }
  __syncthreads();

  if (t >= 512) {
    // -------- producer: 128 threads, 12 x 16B loads per K-iter --------
    const int pt = t - 512;
    const int swz = ((pt & 3) ^ ((pt >> 3) & 3)) * 8;   // source-side XOR swizzle
    const _Float16* xsrc[4];
    #pragma unroll
    for (int j2 = 0; j2 < 4; j2++)
      xsrc[j2] = xh + (long)(sEnt[(pt >> 2) + 32 * j2] >> 1) * D_DIM + swz;
    const int po = (pt >> 2) * 32 + swz;                // swizzled packed offset
    const _Float16* w1t = w1p + (long)(e * 16 + nt) * 32 * 4096 + po;
    const _Float16* w3t = w3p + (long)(e * 16 + nt) * 32 * 4096 + po;
    const int l0 = pt * 8;                              // LDS dest stays linear

    auto stage = [&](int b, int kc) {
      #pragma unroll
      for (int j2 = 0; j2 < 4; j2++)
        gload16(xsrc[j2] + kc * 32, &Xs[b][l0 + j2 * 1024]);
      #pragma unroll
      for (int j2 = 0; j2 < 4; j2++)
        gload16(w1t + (long)kc * 4096 + j2 * 1024, &W1s[b][l0 + j2 * 1024]);
      #pragma unroll
      for (int j2 = 0; j2 < 4; j2++)
        gload16(w3t + (long)kc * 4096 + j2 * 1024, &W3s[b][l0 + j2 * 1024]);
    };

    stage(0, 0); stage(1, 1);
    __asm__ volatile("s_waitcnt vmcnt(12)\n\ts_barrier");   // B0: buf0 ready
    for (int kc = 0; kc < 32; ++kc) {
      if (kc + 2 < 32) {
        stage((kc + 2) % 3, kc + 2);
        __asm__ volatile("s_waitcnt vmcnt(12)\n\ts_barrier");  // buf kc+1 ready
      } else {
        __asm__ volatile("s_waitcnt vmcnt(0)\n\ts_barrier");
      }
    }
    return;
  }

  // -------- consumers: 8 waves, 128x128 tile, 64x32 per wave, dual GEMM ----
  const int w = t >> 6, lane = t & 63;
  const int wm = (w & 1) * 64, wn = (w >> 1) * 32;
  const int q = lane >> 4, lr = lane & 15;
  const int qs = (q ^ ((lr >> 1) & 3)) * 8;             // read-side XOR swizzle

  f32x4 au[4][2], av[4][2];
  const f32x4 zz = {0.f, 0.f, 0.f, 0.f};
  #pragma unroll
  for (int i = 0; i < 4; i++)
    #pragma unroll
    for (int j2 = 0; j2 < 2; j2++) { au[i][j2] = zz; av[i][j2] = zz; }

  __syncthreads();                     // B0
  for (int kc = 0; kc < 32; ++kc) {
    const int p = kc % 3;
    f16x8 a[4], b1[2], b3[2];
    #pragma unroll
    for (int i = 0; i < 4; i++)
      a[i]  = *(const f16x8*)(&Xs[p][(wm + i * 16 + lr) * 32 + qs]);
    #pragma unroll
    for (int i = 0; i < 2; i++) {
      b1[i] = *(const f16x8*)(&W1s[p][(wn + i * 16 + lr) * 32 + qs]);
      b3[i] = *(const f16x8*)(&W3s[p][(wn + i * 16 + lr) * 32 + qs]);
    }
    #pragma unroll
    for (int mi = 0; mi < 4; mi++)
      #pragma unroll
      for (int ni = 0; ni < 2; ni++) {
        au[mi][ni] = __builtin_amdgcn_mfma_f32_16x16x32_f16(a[mi], b1[ni], au[mi][ni], 0, 0, 0);
        av[mi][ni] = __builtin_amdgcn_mfma_f32_16x16x32_f16(a[mi], b3[ni], av[mi][ni], 0, 0, 0);
      }
    __syncthreads();                   // B_{kc+1}
  }

  // epilogue: packed h tile (e, mt), kchunks nt*4 .. nt*4+3, row = list position
  const long tb = ((long)(e * MT1 + mt) * 64 + nt * 4) * 4096;
  #pragma unroll
  for (int mi = 0; mi < 4; mi++) {
    #pragma unroll
    for (int r = 0; r < 4; r++) {
      int ml = wm + mi * 16 + q * 4 + r;
      if (m0 + ml < c) {
        #pragma unroll
        for (int ni = 0; ni < 2; ni++) {
          int colb = wn + ni * 16;
          float u = au[mi][ni][r];
          float rl = u > 0.f ? u : 0.f;
          float hv = rl * rl * av[mi][ni][r];
          hbuf[tb + (long)(colb >> 5) * 4096 + ml * 32 + (colb & 31) + lr] = (_Float16)hv;
        }
      }
    }
  }
}

// ---------------- stage 2: obuf = coef * (h @ W2^T), NO atomics ----------------
// Split-K removed (it only existed to feed atomics); K = 64 chunks per block.
// Epilogue: plain coef-scaled f16 stores to obuf[e*CAPE+pos][1024] — exactly
// one writer per element. combine_out sums each token's two rows.
// 37.7M device-scope f32 atomicAdds (~150 MB serialized L2 RMW) eliminated.
__global__ __launch_bounds__(384, 3) void ffn_stage2(
    const _Float16* __restrict__ hbuf, const _Float16* __restrict__ w2p,
    const int* __restrict__ cnt, const float* __restrict__ coefL,
    _Float16* __restrict__ obuf) {
  const int lin = blockIdx.x;
  const int xcd = lin & 7;
  const int j   = lin >> 3;        // 0..143
  const int mt  = j % MT1;
  const int gi  = j / MT1;         // 0..7
  const int g   = gi * 8 + xcd;    // 0..63 -> (dt, e)
  const int dt  = g & 7;
  const int e   = g >> 3;          // 0..7
  const int m0 = mt * 128;
  const int c = cnt[e];
  if (m0 >= c) return;

  __shared__ _Float16 Hs[3][4096];
  __shared__ _Float16 W2s[3][4096];
  __shared__ float sCoef[128];

  const int t = threadIdx.x;
  if (t < 128) {
    int idx = m0 + t; if (idx >= c) idx = c - 1;
    sCoef[t] = coefL[e * CAPL + idx];
  }
  __syncthreads();

  if (t >= 256) {
    // -------- producer: 8 x 16B loads per K-iter, all linear --------
    const int pt = t - 256;
    const int swz = ((pt & 3) ^ ((pt >> 3) & 3)) * 8;   // source-side XOR swizzle
    const int po = (pt >> 2) * 32 + swz;
    const _Float16* hA  = hbuf + (long)(e * MT1 + mt) * 64 * 4096 + po;
    const _Float16* w2t = w2p  + (long)(e * 8 + dt) * 64 * 4096 + po;
    const int l0 = pt * 8;

    auto stage = [&](int b, int kc) {
      #pragma unroll
      for (int j2 = 0; j2 < 4; j2++)
        gload16(hA + (long)kc * 4096 + j2 * 1024, &Hs[b][l0 + j2 * 1024]);
      #pragma unroll
      for (int j2 = 0; j2 < 4; j2++)
        gload16(w2t + (long)kc * 4096 + j2 * 1024, &W2s[b][l0 + j2 * 1024]);
    };

    stage(0, 0); stage(1, 1);
    __asm__ volatile("s_waitcnt vmcnt(8)\n\ts_barrier");
    for (int kc = 0; kc < 64; ++kc) {
      if (kc + 2 < 64) {
        stage((kc + 2) % 3, kc + 2);
        __asm__ volatile("s_waitcnt vmcnt(8)\n\ts_barrier");
      } else {
        __asm__ volatile("s_waitcnt vmcnt(0)\n\ts_barrier");
      }
    }
    return;
  }

  const int w = t >> 6, lane = t & 63;
  const int wm = (w & 1) * 64, wn = (w >> 1) * 64;
  const int q = lane >> 4, lr = lane & 15;
  const int qs = (q ^ ((lr >> 1) & 3)) * 8;             // read-side XOR swizzle

  f32x4 ac[4][4];
  const f32x4 zz = {0.f, 0.f, 0.f, 0.f};
  #pragma unroll
  for (int i = 0; i < 4; i++)
    #pragma unroll
    for (int j2 = 0; j2 < 4; j2++) ac[i][j2] = zz;

  __syncthreads();
  for (int kc = 0; kc < 64; ++kc) {
    const int p = kc % 3;
    f16x8 a[4], b[4];
    #pragma unroll
    for (int i = 0; i < 4; i++) {
      a[i] = *(const f16x8*)(&Hs[p][(wm + i * 16 + lr) * 32 + qs]);
      b[i] = *(const f16x8*)(&W2s[p][(wn + i * 16 + lr) * 32 + qs]);
    }
    #pragma unroll
    for (int mi = 0; mi < 4; mi++)
      #pragma unroll
      for (int ni = 0; ni < 4; ni++)
        ac[mi][ni] = __builtin_amdgcn_mfma_f32_16x16x32_f16(a[mi], b[ni], ac[mi][ni], 0, 0, 0);
    __syncthreads();
  }

  const int n0 = dt * 128;
  #pragma unroll
  for (int mi = 0; mi < 4; mi++) {
    #pragma unroll
    for (int r = 0; r < 4; r++) {
      int ml = wm + mi * 16 + q * 4 + r;
      if (m0 + ml < c) {
        float cf = sCoef[ml];
        _Float16* op = obuf + ((long)(e * CAPE + m0 + ml)) * D_DIM + n0 + wn + lr;
        #pragma unroll
        for (int ni = 0; ni < 4; ni++)
          op[ni * 16] = (_Float16)(cf * ac[mi][ni][r]);
      }
    }
  }
}

// ---------------- combine: out[n] = obuf[inv[2n]] + obuf[inv[2n+1]] ----------
// 4 tokens/block; each lane handles 16 consecutive cols (f16x8 x2 per row).
__global__ __launch_bounds__(256) void combine_out(
    const _Float16* __restrict__ obuf, const int* __restrict__ inv,
    float* __restrict__ out) {
  const int n = blockIdx.x * 4 + (threadIdx.x >> 6);
  const int lane = threadIdx.x & 63;
  const long r1 = (long)inv[n * 2] * D_DIM;
  const long r2 = (long)inv[n * 2 + 1] * D_DIM;
  const int c0 = lane * 16;
  float* op = out + (long)n * D_DIM + c0;
  #pragma unroll
  for (int h = 0; h < 2; h++) {
    f16x8 v1 = *(const f16x8*)(obuf + r1 + c0 + h * 8);
    f16x8 v2 = *(const f16x8*)(obuf + r2 + c0 + h * 8);
    float4 o0, o1;
    o0.x = (float)v1[0] + (float)v2[0];
    o0.y = (float)v1[1] + (float)v2[1];
    o0.z = (float)v1[2] + (float)v2[2];
    o0.w = (float)v1[3] + (float)v2[3];
    o1.x = (float)v1[4] + (float)v2[4];
    o1.y = (float)v1[5] + (float)v2[5];
    o1.z = (float)v1[6] + (float)v2[6];
    o1.w = (float)v1[7] + (float)v2[7];
    ((float4*)(op + h * 8))[0] = o0;
    ((float4*)(op + h * 8))[1] = o1;
  }
}

extern "C" void kernel_launch(void* const* d_in, const int* in_sizes, int n_in,
                              void* d_out, int out_size, void* d_ws, size_t ws_size,
                              hipStream_t stream) {
  (void)in_sizes; (void)n_in; (void)out_size; (void)ws_size;
  const float* x  = (const float*)d_in[0];
  const float* W1 = (const float*)d_in[1];
  const float* W2 = (const float*)d_in[2];   // dict order: x, W1, W2, W3, gate_w, gate_b
  const float* W3 = (const float*)d_in[3];
  const float* gw = (const float*)d_in[4];
  const float* gb = (const float*)d_in[5];
  float* out = (float*)d_out;

  // workspace layout (fp16 elements), ~194 MB total
  _Float16* xh  = (_Float16*)d_ws;
  _Float16* w1p = xh  + (size_t)N_TOK * D_DIM;
  _Float16* w3p = w1p + (size_t)N_EXP * H_DIM * D_DIM;
  _Float16* w2p = w3p + (size_t)N_EXP * H_DIM * D_DIM;
  _Float16* hb  = w2p + (size_t)N_EXP * H_DIM * D_DIM;           // packed: E*MT1*64*4096
  int*   cnt   = (int*)(hb + (size_t)N_EXP * MT1 * 64 * 4096);
  int*   tokL  = cnt + 16;
  float* coefL = (float*)(tokL + N_EXP * CAPL);
  int*   e12   = (int*)(coefL + N_EXP * CAPL);                   // +32 KB
  float2* pp   = (float2*)(e12 + N_TOK);                         // +64 KB
  int*   inv   = (int*)(pp + N_TOK);                             // +64 KB
  // obuf (37.8 MB f16) aliases w1p/w3p: stage1 is the last reader of w1p/w3p
  // and stage2/combine run strictly after it on the same stream.
  _Float16* obuf = w1p;

  int xn4 = N_TOK * D_DIM / 4;
  cvt_f32_f16<<<(xn4 + 255) / 256, 256, 0, stream>>>(x, xh, xn4);
  pack_w<<<dim3(D_DIM / 32, H_DIM / 128, N_EXP), 256, 0, stream>>>(W1, w1p, H_DIM, D_DIM);
  pack_w<<<dim3(D_DIM / 32, H_DIM / 128, N_EXP), 256, 0, stream>>>(W3, w3p, H_DIM, D_DIM);
  pack_w<<<dim3(H_DIM / 32, D_DIM / 128, N_EXP), 256, 0, stream>>>(W2, w2p, D_DIM, H_DIM);

  gate_compute<<<N_TOK / 4, 256, 0, stream>>>(x, gw, gb, e12, pp);
  build_lists<<<N_EXP, 256, 0, stream>>>(e12, pp, cnt, tokL, coefL, inv);

  ffn_stage1<<<MT1 * 16 * N_EXP, 640, 0, stream>>>(xh, w1p, w3p, cnt, tokL, hb);
  ffn_stage2<<<MT1 * 8 * N_EXP, 384, 0, stream>>>(hb, w2p, cnt, coefL, obuf);
  combine_out<<<N_TOK / 4, 256, 0, stream>>>(obuf, inv, out);
}